// Round 1
// 1930.004 us; speedup vs baseline: 1.1676x; 1.1676x over previous
//
#include <hip/hip_runtime.h>
#include <math.h>

// Problem constants (fixed by reference setup)
#define VTOK 50257
#define VDRAFT 32000
#define HDIM 2048
#define TK 32

typedef __attribute__((ext_vector_type(8))) short bf16x8;   // 8 bf16 (4 VGPRs)
typedef __attribute__((ext_vector_type(4))) float f32x4;    // MFMA accum

// RNE float -> bf16 bits (finite inputs only)
__device__ __forceinline__ short f2bf(float x) {
  unsigned u = __float_as_uint(x);
  unsigned r = (u + 0x7fffu + ((u >> 16) & 1u)) >> 16;
  return (short)r;
}
__device__ __forceinline__ float bf2f(short s) {
  return __uint_as_float(((unsigned)(unsigned short)s) << 16);
}

// ---------------- K1: per-row argmax of logits + passthrough copy ----------------
__global__ __launch_bounds__(256) void k_logits_argmax_copy(
    const float* __restrict__ logits, float* __restrict__ out, int* __restrict__ tgt)
{
  const int row = blockIdx.x;
  const size_t base = (size_t)row * VTOK;
  const float* src = logits + base;
  float* dst = out + base;
  const int tid = threadIdx.x;
  float best = -INFINITY; int bi = 0;
  for (int j = tid; j < VTOK; j += 256) {
    float v = src[j];
    dst[j] = v;
    if (v > best) { best = v; bi = j; }   // strict > keeps lowest index (ascending scan)
  }
  __shared__ float sv[256];
  __shared__ int   si[256];
  sv[tid] = best; si[tid] = bi;
  __syncthreads();
  for (int s = 128; s > 0; s >>= 1) {
    if (tid < s) {
      float v = sv[tid + s]; int ix = si[tid + s];
      if (v > sv[tid] || (v == sv[tid] && ix < si[tid])) { sv[tid] = v; si[tid] = ix; }
    }
    __syncthreads();
  }
  if (tid == 0) tgt[row] = si[0];
}

// ---------------- K2: accepted / num_accepted / gather indices / iter-0 ids ----------------
__global__ void k_setup(const int* __restrict__ t, const int* __restrict__ draft,
                        const int* __restrict__ gctx,
                        float* __restrict__ out_acc, float* __restrict__ out_na,
                        float* __restrict__ out_next, int* __restrict__ ids_sel,
                        int* __restrict__ gidx)
{
  const int r = threadIdx.x;
  if (r >= 64) return;
  if (r < 32) {
    int tok = t[r];
    out_acc[r*5+0] = (float)tok;
    out_acc[r*5+1] = 0.f; out_acc[r*5+2] = 0.f; out_acc[r*5+3] = 0.f; out_acc[r*5+4] = 0.f;
    out_na[r] = 1.f;
    out_next[r*5+0] = (float)tok;   // last_acc
    ids_sel[r] = tok;
    gidx[r] = gctx[r];
  } else {
    int g = r - 32;
    int base = 32 + 5*g;
    int m = 0; bool ok = true;
    #pragma unroll
    for (int j = 0; j < 4; j++) {
      int tt = t[base + j];
      out_acc[r*5+j] = (float)tt;
      if (ok && draft[4*g + j] == tt) m++; else ok = false;
    }
    out_acc[r*5+4] = (float)t[base + 4];
    int na = 1 + m;
    out_na[r] = (float)na;
    int last = t[base + na - 1];
    out_next[r*5+0] = (float)last;  // last_acc
    ids_sel[r] = last;
    gidx[r] = 16384 + 5*g + na - 1;
  }
}

// ---------------- Skinny GEMM: C(64 x N) = A(64 x K, gathered rows) @ B(K x N) ----------------
// (fp32 vector path; used for W_fc and W_h only — ARGMAX=1 path retained but uninstantiated)
template<int ARGMAX>
__global__ __launch_bounds__(256) void k_gemm64(
    const float* __restrict__ A, const int* __restrict__ rowmap, int lda,
    const float* __restrict__ B, int ldb, int kchunk,
    float* __restrict__ P, int Pstride,
    float* __restrict__ pval, int* __restrict__ pidx)
{
  const int tid = threadIdx.x;
  const int j0 = blockIdx.x * 64;
  const int k0 = blockIdx.y * kchunk;
  const int tr = tid & 15;        // row group (4 rows)
  const int tc = tid >> 4;        // col group (4 cols)

  __shared__ float sA[TK * 66];   // transposed [kk][row], stride 66
  __shared__ float sB[TK * 64];   // [kk][col]

  float acc[4][4];
  #pragma unroll
  for (int i = 0; i < 4; i++)
    #pragma unroll
    for (int j = 0; j < 4; j++) acc[i][j] = 0.f;

  const int arow = tid >> 2;           // 0..63
  const int kseg = (tid & 3) * 8;      // 0,8,16,24
  const int asrc = rowmap ? rowmap[arow] : arow;
  const float* Ap = A + (size_t)asrc * lda + k0 + kseg;

  const int bk = tid >> 3;             // 0..31
  const int bj = (tid & 7) * 8;        // 0..56
  const float* Bp = B + (size_t)(k0 + bk) * ldb + j0 + bj;

  for (int kb = 0; kb < kchunk; kb += TK) {
    float4 a0 = *(const float4*)(Ap);
    float4 a1 = *(const float4*)(Ap + 4);
    float4 b0 = *(const float4*)(Bp);
    float4 b1 = *(const float4*)(Bp + 4);
    Ap += TK;
    Bp += (size_t)TK * ldb;
    __syncthreads();   // previous compute done before overwriting LDS
    sA[(kseg+0)*66 + arow] = a0.x;
    sA[(kseg+1)*66 + arow] = a0.y;
    sA[(kseg+2)*66 + arow] = a0.z;
    sA[(kseg+3)*66 + arow] = a0.w;
    sA[(kseg+4)*66 + arow] = a1.x;
    sA[(kseg+5)*66 + arow] = a1.y;
    sA[(kseg+6)*66 + arow] = a1.z;
    sA[(kseg+7)*66 + arow] = a1.w;
    *(float4*)&sB[bk*64 + bj]     = b0;
    *(float4*)&sB[bk*64 + bj + 4] = b1;
    __syncthreads();
    #pragma unroll
    for (int kk = 0; kk < TK; kk++) {
      float2 a01 = *(const float2*)&sA[kk*66 + tr*4];
      float2 a23 = *(const float2*)&sA[kk*66 + tr*4 + 2];
      float4 bv  = *(const float4*)&sB[kk*64 + tc*4];
      float av[4] = {a01.x, a01.y, a23.x, a23.y};
      float bw[4] = {bv.x, bv.y, bv.z, bv.w};
      #pragma unroll
      for (int i = 0; i < 4; i++)
        #pragma unroll
        for (int j = 0; j < 4; j++)
          acc[i][j] = fmaf(av[i], bw[j], acc[i][j]);
    }
  }

  if (ARGMAX == 0) {
    float* Pd = P + (size_t)blockIdx.y * 64 * Pstride;
    #pragma unroll
    for (int i = 0; i < 4; i++) {
      float4 v = make_float4(acc[i][0], acc[i][1], acc[i][2], acc[i][3]);
      *(float4*)&Pd[(size_t)(tr*4 + i) * Pstride + j0 + tc*4] = v;
    }
  } else {
    __syncthreads();
    float* rv = sA;
    int*   ri = (int*)sB;
    #pragma unroll
    for (int i = 0; i < 4; i++) {
      float b_ = acc[i][0]; int x_ = j0 + tc*4;
      #pragma unroll
      for (int j = 1; j < 4; j++)
        if (acc[i][j] > b_) { b_ = acc[i][j]; x_ = j0 + tc*4 + j; }
      rv[(tr*4 + i) * 16 + tc] = b_;
      ri[(tr*4 + i) * 16 + tc] = x_;
    }
    __syncthreads();
    if (tid < 64) {
      const int r = tid;
      float b_ = rv[r*16]; int x_ = ri[r*16];
      #pragma unroll 4
      for (int c = 1; c < 16; c++) {
        float v = rv[r*16 + c]; int ix = ri[r*16 + c];
        if (v > b_ || (v == b_ && ix < x_)) { b_ = v; x_ = ix; }
      }
      pval[(size_t)blockIdx.x * 64 + r] = b_;
      pidx[(size_t)blockIdx.x * 64 + r] = x_;
    }
  }
}

// ---------------- deterministic K-split reduction (4 partials) ----------------
__global__ __launch_bounds__(256) void k_reduce4(const float* __restrict__ P, float* __restrict__ outb)
{
  const int i = blockIdx.x * 256 + threadIdx.x;   // float4 index; 32768 total
  const float4* p = (const float4*)P;
  float4 s  = p[i];
  float4 t1 = p[i + 32768];
  float4 t2 = p[i + 65536];
  float4 t3 = p[i + 98304];
  s.x += t1.x + t2.x + t3.x;
  s.y += t1.y + t2.y + t3.y;
  s.z += t1.z + t2.z + t3.z;
  s.w += t1.w + t2.w + t3.w;
  ((float4*)outb)[i] = s;
}

// ---------------- reduction + embed gather + tanh + bf16 hi/lo split of h_new ----------------
__global__ __launch_bounds__(256) void k_reduce4_tanh(
    const float* __restrict__ P, const float* __restrict__ embed,
    const int* __restrict__ ids, float* __restrict__ outb,
    short* __restrict__ Ahi, short* __restrict__ Alo)
{
  const int i = blockIdx.x * 256 + threadIdx.x;   // float4 index over (64 x 2048)
  const int r  = i >> 9;                          // 512 float4 per row
  const int c4 = i & 511;
  const float4* p = (const float4*)P;
  float4 s  = p[i];
  float4 t1 = p[i + 32768];
  float4 t2 = p[i + 65536];
  float4 t3 = p[i + 98304];
  const float4 e = *(const float4*)(embed + (size_t)ids[r] * HDIM + c4*4);
  float4 o;
  o.x = tanhf(e.x + (s.x + t1.x + t2.x + t3.x));
  o.y = tanhf(e.y + (s.y + t1.y + t2.y + t3.y));
  o.z = tanhf(e.z + (s.z + t1.z + t2.z + t3.z));
  o.w = tanhf(e.w + (s.w + t1.w + t2.w + t3.w));
  ((float4*)outb)[i] = o;
  // bf16 split for MFMA A-operand: o = hi + lo (~16 mantissa bits kept)
  short4 h, l;
  h.x = f2bf(o.x); l.x = f2bf(o.x - bf2f(h.x));
  h.y = f2bf(o.y); l.y = f2bf(o.y - bf2f(h.y));
  h.z = f2bf(o.z); l.z = f2bf(o.z - bf2f(h.z));
  h.w = f2bf(o.w); l.w = f2bf(o.w - bf2f(h.w));
  *(short4*)&Ahi[i*4] = h;
  *(short4*)&Alo[i*4] = l;
}

// ---------------- lm_head GEMM via bf16x3 MFMA, fused per-block row-argmax ----------------
// C(64 x 32000) = h_new(64 x 2048) @ lm_head(2048 x 32000), fp32-comparable precision:
//   C = Ahi*Bhi + Ahi*Blo + Alo*Bhi  (each split RNE bf16, fp32 accum)
// grid = 500 col-blocks of 64. Wave w owns rows 16w..16w+15 (A frags direct from L2).
// B tile (32 x 64) staged fp32->hi/lo bf16, TRANSPOSED [col][k] with 40-short padded
// rows (16B-aligned b128, even bank spread). Single-barrier double buffer.
__global__ __launch_bounds__(256) void k_lm_mfma(
    const short* __restrict__ Ahi, const short* __restrict__ Alo,
    const float* __restrict__ B,
    float* __restrict__ pval, int* __restrict__ pidx)
{
  const int tid  = threadIdx.x;
  const int lane = tid & 63;
  const int w    = tid >> 6;            // wave 0..3
  const int j0   = blockIdx.x * 64;

  __shared__ short sBh[2][64 * 40];     // [buf][col][k] hi, 40-short padded rows
  __shared__ short sBl[2][64 * 40];     // lo

  // staging coords: thread (col=lane, k-quarter=w) owns an 8-k strip
  const int sdst = lane * 40 + w * 8;

  // MFMA operand coords (verified m89 layouts):
  //   A frag: row = lane&15 (+16w), k = 8*(lane>>4)+t
  //   B frag: col = lane&15 (+16cb), k = 8*(lane>>4)+t
  const short* Aph = Ahi + (((w << 4) + (lane & 15)) * 2048) + ((lane >> 4) << 3);
  const short* Apl = Alo + (((w << 4) + (lane & 15)) * 2048) + ((lane >> 4) << 3);
  const int bro = (lane & 15) * 40 + ((lane >> 4) << 3);

  f32x4 acc[4];
  #pragma unroll
  for (int cb = 0; cb < 4; cb++) acc[cb] = (f32x4){0.f, 0.f, 0.f, 0.f};

  const float* Bp = B + (size_t)(w * 8) * VDRAFT + j0 + lane;

  // prologue: k-tile 0 -> buffer 0
  {
    bf16x8 hv, lv;
    #pragma unroll
    for (int u = 0; u < 8; u++) {
      float v = Bp[(size_t)u * VDRAFT];
      short h = f2bf(v);
      hv[u] = h; lv[u] = f2bf(v - bf2f(h));
    }
    *(bf16x8*)&sBh[0][sdst] = hv;
    *(bf16x8*)&sBl[0][sdst] = lv;
  }
  Bp += (size_t)32 * VDRAFT;

  for (int kt = 0; kt < 64; kt++) {
    const int p = kt & 1;
    float nv[8];
    if (kt < 63) {                       // issue next tile's global loads early
      #pragma unroll
      for (int u = 0; u < 8; u++) nv[u] = Bp[(size_t)u * VDRAFT];
      Bp += (size_t)32 * VDRAFT;
    }
    bf16x8 ah = *(const bf16x8*)(Aph + kt * 32);
    bf16x8 al = *(const bf16x8*)(Apl + kt * 32);
    __syncthreads();                     // buf p staged; prior reads of buf p^1 done
    #pragma unroll
    for (int cb = 0; cb < 4; cb++) {
      bf16x8 bh = *(const bf16x8*)&sBh[p][cb * 640 + bro];
      bf16x8 bl = *(const bf16x8*)&sBl[p][cb * 640 + bro];
      acc[cb] = __builtin_amdgcn_mfma_f32_16x16x32_bf16(ah, bh, acc[cb], 0, 0, 0);
      acc[cb] = __builtin_amdgcn_mfma_f32_16x16x32_bf16(ah, bl, acc[cb], 0, 0, 0);
      acc[cb] = __builtin_amdgcn_mfma_f32_16x16x32_bf16(al, bh, acc[cb], 0, 0, 0);
    }
    if (kt < 63) {                       // convert + stage into the other buffer
      bf16x8 hv, lv;
      #pragma unroll
      for (int u = 0; u < 8; u++) {
        short h = f2bf(nv[u]);
        hv[u] = h; lv[u] = f2bf(nv[u] - bf2f(h));
      }
      *(bf16x8*)&sBh[p ^ 1][sdst] = hv;
      *(bf16x8*)&sBl[p ^ 1][sdst] = lv;
    }
  }

  // fused per-row argmax over this block's 64 cols.
  // D layout: row = 16w + 4*(lane>>4) + reg, col = j0 + 16cb + (lane&15)
  const int colbase = j0 + (lane & 15);
  #pragma unroll
  for (int r = 0; r < 4; r++) {
    float bv = acc[0][r]; int bc = colbase;
    #pragma unroll
    for (int cb = 1; cb < 4; cb++) {
      float v2 = acc[cb][r]; int c2 = colbase + 16*cb;
      if (v2 > bv) { bv = v2; bc = c2; }      // strict > keeps lowest col
    }
    #pragma unroll
    for (int m = 1; m < 16; m <<= 1) {        // reduce across the 16 col-lanes
      float ov = __shfl_xor(bv, m);
      int   oc = __shfl_xor(bc, m);
      if (ov > bv || (ov == bv && oc < bc)) { bv = ov; bc = oc; }
    }
    if ((lane & 15) == 0) {
      int row = (w << 4) + ((lane >> 4) << 2) + r;
      pval[(size_t)blockIdx.x * 64 + row] = bv;
      pidx[(size_t)blockIdx.x * 64 + row] = bc;
    }
  }
}

// ---------------- final argmax across 500 column blocks + d2t + outputs ----------------
__global__ void k_finalize(const float* __restrict__ pval, const int* __restrict__ pidx,
                           const int* __restrict__ d2t,
                           float* __restrict__ out_draft, float* __restrict__ out_next,
                           int* __restrict__ ids, int iter)
{
  const int r = threadIdx.x;   // 64 threads
  float b_ = pval[r]; int x_ = pidx[r];
  for (int b = 1; b < 500; b++) {
    float v = pval[b*64 + r]; int ix = pidx[b*64 + r];
    if (v > b_ || (v == b_ && ix < x_)) { b_ = v; x_ = ix; }
  }
  int tok = d2t[x_] + x_;
  out_draft[r*4 + iter]     = (float)tok;
  out_next[r*5 + iter + 1]  = (float)tok;
  ids[r] = tok;
}

extern "C" void kernel_launch(void* const* d_in, const int* in_sizes, int n_in,
                              void* d_out, int out_size, void* d_ws, size_t ws_size,
                              hipStream_t stream)
{
  const float* logits = (const float*)d_in[0];
  // d_in[1] input_ids, d_in[2] position_ids: provably unused by the outputs
  const float* cap    = (const float*)d_in[3];
  const int*   draft  = (const int*)d_in[4];
  const int*   gctx   = (const int*)d_in[5];
  const float* Wfc    = (const float*)d_in[6];
  const float* embed  = (const float*)d_in[7];
  const float* Wh     = (const float*)d_in[8];
  const float* lmh    = (const float*)d_in[9];
  const int*   d2t    = (const int*)d_in[10];
  float* out = (float*)d_out;

  char* wsb = (char*)d_ws;
  int*   t_ws    = (int*)(wsb + 0);                       // 192 ints
  int*   ids_ws  = (int*)(wsb + 1024);                    // 64 ints
  int*   gidx_ws = (int*)(wsb + 1536);                    // 64 ints
  float* pval    = (float*)(wsb + 4096);                  // 500*64 f32
  int*   pidx    = (int*)(wsb + 4096 + 128000);           // 500*64 int
  float* P       = (float*)(wsb + 262144);                // 4*64*2048 f32 = 2 MB
  float* hA      = (float*)(wsb + 262144 + 2097152);      // 64*2048 f32
  float* hB      = (float*)(wsb + 262144 + 2097152 + 524288);
  short* Ahi     = (short*)(wsb + 3407872);               // 64*2048 bf16 bits (256 KB)
  short* Alo     = (short*)(wsb + 3670016);               // 64*2048 bf16 bits (256 KB)

  // Output layout (flat float32, return order): logits, accepted, num_accepted,
  // next_draft_tokens, next_new_tokens
  const size_t O1 = 9649344;  // accepted (64x5)
  const size_t O2 = 9649664;  // num_accepted (64)
  const size_t O3 = 9649728;  // next_draft_tokens (64x4)
  const size_t O4 = 9649984;  // next_new_tokens (64x5)

  k_logits_argmax_copy<<<192, 256, 0, stream>>>(logits, out, t_ws);
  k_setup<<<1, 64, 0, stream>>>(t_ws, draft, gctx, out + O1, out + O2, out + O4, ids_ws, gidx_ws);

  // hidden_sel = captured_hidden[gidx] @ W_fc  (K=6144, split 4x1536)
  k_gemm64<0><<<dim3(32, 4), 256, 0, stream>>>(cap, gidx_ws, 6144, Wfc, 2048, 1536, P, 2048, nullptr, nullptr);
  k_reduce4<<<128, 256, 0, stream>>>(P, hA);

  float* bufs[2] = {hA, hB};
  const float* cur = hA;
  for (int i = 0; i < 4; i++) {
    float* nxt = bufs[(i + 1) & 1];
    // h @ W_h  (K=2048, split 4x512)
    k_gemm64<0><<<dim3(32, 4), 256, 0, stream>>>(cur, nullptr, HDIM, Wh, HDIM, 512, P, HDIM, nullptr, nullptr);
    // h_new = tanh(embed[ids] + .), + bf16 hi/lo split for MFMA
    k_reduce4_tanh<<<128, 256, 0, stream>>>(P, embed, ids_ws, nxt, Ahi, Alo);
    // logits_d = h_new @ lm_head via bf16x3 MFMA, fused per-block argmax
    k_lm_mfma<<<500, 256, 0, stream>>>(Ahi, Alo, lmh, pval, pidx);
    k_finalize<<<1, 64, 0, stream>>>(pval, pidx, d2t, out + O3, out + O4, ids_ws, i);
    cur = nxt;
  }
}